// Round 9
// baseline (192.792 us; speedup 1.0000x reference)
//
#include <hip/hip_runtime.h>

// EnhancedMoEModel: B=524288, D=32, H=64, H2=32, E=8, O=1. fp32 in/out.
// out[b] = sum_e sigmoid(relu(relu(x W1e + b1e) W2e + b2e) W3e + b3e) * probs[b,e]
//
// Expert-stationary MFMA: wave w owns expert w; packed weight fragments are
// loop-invariant. Layers transposed (M=hidden, N=16 rows): layer1 C-frag ==
// layer2 B-frag; layer3 = MFMA with w3 replicated across rows. No shuffles.
// R8 lesson: R5/R6/R8 all pin at ~106us kernel despite different VALU mixes
// -> latency-bound serial chain at 3.4 waves/EU, NOT issue-bound. R9: two
// independent 16-row tiles per iteration (2x ILP on every chain link) +
// single-op v_cvt_pk_bf16_f32 pack (gfx950).

constexpr int RB = 512;   // rows per block; 8 waves x 16 iters of 32 rows

typedef __attribute__((ext_vector_type(4))) short bf16x4;
typedef __attribute__((ext_vector_type(8))) short bf16x8;
typedef __attribute__((ext_vector_type(4))) float f32x4;

__device__ __forceinline__ short f2bf_rne(float f) {
    unsigned u = __float_as_uint(f);
    unsigned r = (u + 0x7fffu + ((u >> 16) & 1u)) >> 16;
    return (short)r;
}

// pack two fp32 -> dword of 2 bf16. gfx950 has a single-op packed convert.
__device__ __forceinline__ unsigned pk2(float lo, float hi) {
#if __has_builtin(__builtin_amdgcn_cvt_pk_bf16_f32)
    typedef __attribute__((ext_vector_type(2))) __bf16 nbf2;
    union { nbf2 v; unsigned u; } t;
    t.v = __builtin_amdgcn_cvt_pk_bf16_f32(lo, hi);
    return t.u;
#else
    unsigned ulo = __float_as_uint(lo) + 0x8000u;
    unsigned uhi = __float_as_uint(hi) + 0x8000u;
    return __builtin_amdgcn_perm(uhi, ulo, 0x07060302u);
#endif
}

__device__ __forceinline__ f32x4 mfma16(bf16x4 a, bf16x4 b, f32x4 c) {
#if __has_builtin(__builtin_amdgcn_mfma_f32_16x16x16bf16_1k)
    return __builtin_amdgcn_mfma_f32_16x16x16bf16_1k(a, b, c, 0, 0, 0);
#elif __has_builtin(__builtin_amdgcn_mfma_f32_16x16x16_bf16)
    return __builtin_amdgcn_mfma_f32_16x16x16_bf16(a, b, c, 0, 0, 0);
#else
    asm volatile("v_mfma_f32_16x16x16_bf16 %0, %1, %2, %0\n\t"
                 "s_nop 7\n\ts_nop 3"
                 : "+v"(c) : "v"(a), "v"(b));
    return c;
#endif
}

// d_ws layout: w1p[8][4][64][8] bf16 @0 ; w2p[8][2][4][64][4] bf16 @16384 sh;
// b1p[8][64][16] f32 @ short-offset 32768 ; b2p[8][64][8] f32 ;
// a3p[8][2][64][4] bf16 @ short-offset 57344 (w3 replicated A-fragment).
__global__ void cvt_pack(const float* __restrict__ W1, const float* __restrict__ b1,
                         const float* __restrict__ W2, const float* __restrict__ b2,
                         const float* __restrict__ W3, short* __restrict__ ws) {
    int i = blockIdx.x * blockDim.x + threadIdx.x;   // 16384 threads
    short* w1p = ws;
    short* w2p = ws + 16384;
    float* b1p = (float*)(ws + 32768);
    float* b2p = b1p + 8192;
    short* a3p = ws + 57344;
    if (i < 16384) {
        {   // w1p[e][mt][lane][j] = W1[e][d=8q+j][h=16mt+n]  (A-frag, K=32)
            int j = i & 7, lane = (i >> 3) & 63, mt = (i >> 9) & 3, e = i >> 11;
            int n = lane & 15, q = lane >> 4;
            w1p[i] = f2bf_rne(W1[(e * 32 + q * 8 + j) * 64 + 16 * mt + n]);
        }
        {   // w2p[e][mt2][kb][lane][j] = W2[e][h=16kb+4q+j][h2=16mt2+n]
            int j = i & 3, lane = (i >> 2) & 63, kb = (i >> 8) & 3,
                mt2 = (i >> 10) & 1, e = i >> 11;
            int n = lane & 15, q = lane >> 4;
            w2p[i] = f2bf_rne(W2[(e * 64 + 16 * kb + 4 * q + j) * 32 + 16 * mt2 + n]);
        }
    }
    if (i < 8192) {   // b1p[e][lane][mt*4+r] = b1[e][16mt+4q+r]
        int idx = i & 15, lane = (i >> 4) & 63, e = i >> 10;
        int q = lane >> 4;
        b1p[i] = b1[e * 64 + 16 * (idx >> 2) + 4 * q + (idx & 3)];
    }
    if (i < 4096) {
        {   // b2p[e][lane][mt2*4+r] = b2[e][16mt2+4q+r]
            int idx = i & 7, lane = (i >> 3) & 63, e = i >> 9;
            int q = lane >> 4;
            b2p[i] = b2[e * 32 + 16 * (idx >> 2) + 4 * q + (idx & 3)];
        }
        {   // a3p[e][mt2][lane][j] = W3[e][16mt2+4q+j]  (A-frag, rows replicated)
            int j = i & 3, lane = (i >> 2) & 63, mt2 = (i >> 8) & 1, e = i >> 9;
            int q = lane >> 4;
            a3p[i] = f2bf_rne(W3[e * 32 + 16 * mt2 + 4 * q + j]);
        }
    }
}

__attribute__((amdgpu_flat_work_group_size(512, 512), amdgpu_waves_per_eu(3, 4)))
__global__ void moe_main(const float* __restrict__ x,
                         const float* __restrict__ probs,
                         const short* __restrict__ ws,
                         const float* __restrict__ b3,
                         float* __restrict__ out) {
    __shared__ float sbuf[8][RB];
    const int tid = threadIdx.x;
    const int w = tid >> 6, lane = tid & 63, n = lane & 15, q = lane >> 4;

    const short* w1p = ws;
    const short* w2p = ws + 16384;
    const float* b1p = (const float*)(ws + 32768);
    const float* b2p = b1p + 8192;
    const short* a3p = ws + 57344;

    // Loop-invariant per-expert fragments (resident across the loop).
    bf16x8 w1f[4];
    #pragma unroll
    for (int mt = 0; mt < 4; ++mt)
        w1f[mt] = *(const bf16x8*)(w1p + ((w * 4 + mt) * 64 + lane) * 8);
    bf16x4 w2f[2][4];
    #pragma unroll
    for (int mt2 = 0; mt2 < 2; ++mt2)
        #pragma unroll
        for (int kb = 0; kb < 4; ++kb)
            w2f[mt2][kb] = *(const bf16x4*)(w2p + (((w * 2 + mt2) * 4 + kb) * 64 + lane) * 4);
    f32x4 b1f[4];
    #pragma unroll
    for (int mt = 0; mt < 4; ++mt)
        b1f[mt] = *(const f32x4*)(b1p + (w * 64 + lane) * 16 + mt * 4);
    f32x4 b2f[2];
    bf16x4 a3f[2];
    #pragma unroll
    for (int mt2 = 0; mt2 < 2; ++mt2) {
        b2f[mt2] = *(const f32x4*)(b2p + (w * 64 + lane) * 8 + mt2 * 4);
        a3f[mt2] = *(const bf16x4*)(a3p + ((w * 2 + mt2) * 64 + lane) * 4);
    }
    const float b3v = b3[w];

    const size_t rowbase = (size_t)blockIdx.x * RB;
    // Two 16-row tiles in flight per iteration: tile0 rows it*32+n,
    // tile1 rows it*32+16+n. 16 iterations of 32 rows.
    const float* xp0 = x + (rowbase + n) * 32 + q * 8;      // +1024 per iter
    const float* xp1 = xp0 + 16 * 32;
    const float* pp0 = probs + (rowbase + n) * 8 + w;       // +256 per iter
    const float* pp1 = pp0 + 128;
    float* sb = &sbuf[w][n];

    f32x4 xa0 = *(const f32x4*)xp0, xb0 = *(const f32x4*)(xp0 + 4);
    f32x4 xa1 = *(const f32x4*)xp1, xb1 = *(const f32x4*)(xp1 + 4);
    float pb0 = pp0[0], pb1 = pp1[0];

    for (int it = 0; it < RB / 32; ++it) {
        const int adv = (it < RB / 32 - 1) ? 1 : 0;
        xp0 += 1024 * adv; xp1 += 1024 * adv;
        pp0 += 256 * adv;  pp1 += 256 * adv;
        f32x4 na0 = *(const f32x4*)xp0, nb0 = *(const f32x4*)(xp0 + 4);
        f32x4 na1 = *(const f32x4*)xp1, nb1 = *(const f32x4*)(xp1 + 4);
        float npb0 = pp0[0], npb1 = pp1[0];

        // X^T B-fragments (lane holds x[row=n][d=8q..8q+7]).
        union { bf16x8 v; unsigned u[4]; } xf0, xf1;
        xf0.u[0] = pk2(xa0.x, xa0.y); xf0.u[1] = pk2(xa0.z, xa0.w);
        xf0.u[2] = pk2(xb0.x, xb0.y); xf0.u[3] = pk2(xb0.z, xb0.w);
        xf1.u[0] = pk2(xa1.x, xa1.y); xf1.u[1] = pk2(xa1.z, xa1.w);
        xf1.u[2] = pk2(xb1.x, xb1.y); xf1.u[3] = pk2(xb1.z, xb1.w);

        // Layer 1: 4x mfma 16x16x32 per tile, C-init = b1 fragment.
        f32x4 c1_0[4], c1_1[4];
        #pragma unroll
        for (int mt = 0; mt < 4; ++mt) {
            c1_0[mt] = __builtin_amdgcn_mfma_f32_16x16x32_bf16(w1f[mt], xf0.v, b1f[mt], 0, 0, 0);
            c1_1[mt] = __builtin_amdgcn_mfma_f32_16x16x32_bf16(w1f[mt], xf1.v, b1f[mt], 0, 0, 0);
        }

        // relu + pack: C1 fragment == B fragment (k=4q+r) for 16x16x16.
        bf16x4 p0[4], p1[4];
        #pragma unroll
        for (int mt = 0; mt < 4; ++mt) {
            union { bf16x4 v; unsigned u[2]; } t0, t1;
            t0.u[0] = pk2(fmaxf(c1_0[mt].x, 0.f), fmaxf(c1_0[mt].y, 0.f));
            t0.u[1] = pk2(fmaxf(c1_0[mt].z, 0.f), fmaxf(c1_0[mt].w, 0.f));
            t1.u[0] = pk2(fmaxf(c1_1[mt].x, 0.f), fmaxf(c1_1[mt].y, 0.f));
            t1.u[1] = pk2(fmaxf(c1_1[mt].z, 0.f), fmaxf(c1_1[mt].w, 0.f));
            p0[mt] = t0.v; p1[mt] = t1.v;
        }

        // Layer 2: 2 M-tiles x 4 K-blocks of 16x16x16 per tile; the two
        // tiles' serial K-chains interleave in the matrix pipe.
        f32x4 c2_0[2], c2_1[2];
        #pragma unroll
        for (int mt2 = 0; mt2 < 2; ++mt2) {
            f32x4 a0 = b2f[mt2], a1 = b2f[mt2];
            #pragma unroll
            for (int kb = 0; kb < 4; ++kb) {
                a0 = mfma16(w2f[mt2][kb], p0[kb], a0);
                a1 = mfma16(w2f[mt2][kb], p1[kb], a1);
            }
            c2_0[mt2] = a0; c2_1[mt2] = a1;
        }

        // relu + pack H2 -> B-fragments for the layer-3 MFMA.
        bf16x4 pc2_0[2], pc2_1[2];
        #pragma unroll
        for (int mt2 = 0; mt2 < 2; ++mt2) {
            union { bf16x4 v; unsigned u[2]; } t0, t1;
            t0.u[0] = pk2(fmaxf(c2_0[mt2].x, 0.f), fmaxf(c2_0[mt2].y, 0.f));
            t0.u[1] = pk2(fmaxf(c2_0[mt2].z, 0.f), fmaxf(c2_0[mt2].w, 0.f));
            t1.u[0] = pk2(fmaxf(c2_1[mt2].x, 0.f), fmaxf(c2_1[mt2].y, 0.f));
            t1.u[1] = pk2(fmaxf(c2_1[mt2].z, 0.f), fmaxf(c2_1[mt2].w, 0.f));
            pc2_0[mt2] = t0.v; pc2_1[mt2] = t1.v;
        }

        // Layer 3 on the matrix pipe: A = w3 replicated -> D[m][n]=s[n].
        f32x4 b3c = {b3v, b3v, b3v, b3v};
        f32x4 s0 = mfma16(a3f[0], pc2_0[0], b3c);
        f32x4 s1 = mfma16(a3f[0], pc2_1[0], b3c);
        s0 = mfma16(a3f[1], pc2_0[1], s0);
        s1 = mfma16(a3f[1], pc2_1[1], s1);

        const float sig0 = 1.f / (1.f + __expf(-s0.x));
        const float sig1 = 1.f / (1.f + __expf(-s1.x));
        if (q == 0) {
            sb[it * 32]      = sig0 * pb0;
            sb[it * 32 + 16] = sig1 * pb1;
        }

        xa0 = na0; xb0 = nb0; xa1 = na1; xb1 = nb1;
        pb0 = npb0; pb1 = npb1;
    }

    __syncthreads();
    // Combine experts: thread t sums sbuf[0..7][t]; coalesced 2 KB store.
    float r = 0.f;
    #pragma unroll
    for (int e = 0; e < 8; ++e) r += sbuf[e][tid];
    out[rowbase + tid] = r;
}

extern "C" void kernel_launch(void* const* d_in, const int* in_sizes, int n_in,
                              void* d_out, int out_size, void* d_ws, size_t ws_size,
                              hipStream_t stream) {
    const float* x     = (const float*)d_in[0];
    const float* probs = (const float*)d_in[1];
    const float* W1    = (const float*)d_in[2];
    const float* b1    = (const float*)d_in[3];
    const float* W2    = (const float*)d_in[4];
    const float* b2    = (const float*)d_in[5];
    const float* W3    = (const float*)d_in[6];
    const float* b3    = (const float*)d_in[7];

    short* ws = (short*)d_ws;
    const int nrows = in_sizes[0] / 32;          // 524288

    hipLaunchKernelGGL(cvt_pack, dim3(64), dim3(256), 0, stream,
                       W1, b1, W2, b2, W3, ws);
    hipLaunchKernelGGL(moe_main, dim3(nrows / RB), dim3(512), 0, stream,
                       x, probs, ws, b3, (float*)d_out);
}

// Round 10
// 190.115 us; speedup vs baseline: 1.0141x; 1.0141x over previous
//
#include <hip/hip_runtime.h>

// EnhancedMoEModel: B=524288, D=32, H=64, H2=32, E=8, O=1. fp32 in/out.
// out[b] = sum_e sigmoid(relu(relu(x W1e + b1e) W2e + b2e) W3e + b3e) * probs[b,e]
//
// Expert-stationary MFMA, all layers on the ONE verified gfx950 builtin
// __builtin_amdgcn_mfma_f32_16x16x32_bf16 (R5-R9 used 16x16x16 via an inline
// asm fallback with s_nop 7+3 bubbles -> ~16cyc/MFMA, the invariant 106us).
// Zero-shuffle chaining via column permutation: hidden unit
//   h = 32*(mt>>1) + 8q + 4*(mt&1) + r
// makes each lane's layer-N output exactly the k=8q+j B-fragment of the
// next layer's K=32 MFMA. Layer3 = one MFMA with w3 replicated over rows.

constexpr int RB = 512;   // rows per block; 8 waves x 16 iters of 32 rows

typedef __attribute__((ext_vector_type(8))) short bf16x8;
typedef __attribute__((ext_vector_type(4))) float f32x4;

__device__ __forceinline__ short f2bf_rne(float f) {
    unsigned u = __float_as_uint(f);
    unsigned r = (u + 0x7fffu + ((u >> 16) & 1u)) >> 16;
    return (short)r;
}

// pack two fp32 -> dword of 2 bf16 (single-op on gfx950 if available).
__device__ __forceinline__ unsigned pk2(float lo, float hi) {
#if __has_builtin(__builtin_amdgcn_cvt_pk_bf16_f32)
    typedef __attribute__((ext_vector_type(2))) __bf16 nbf2;
    union { nbf2 v; unsigned u; } t;
    t.v = __builtin_amdgcn_cvt_pk_bf16_f32(lo, hi);
    return t.u;
#else
    unsigned ulo = __float_as_uint(lo) + 0x8000u;
    unsigned uhi = __float_as_uint(hi) + 0x8000u;
    return __builtin_amdgcn_perm(uhi, ulo, 0x07060302u);
#endif
}

#define MFMA32(a, b, c) __builtin_amdgcn_mfma_f32_16x16x32_bf16((a), (b), (c), 0, 0, 0)

// d_ws layout (short offsets): w1p[8][4][64][8] @0 ; w2p[8][2][2][64][8] @16384 ;
// b1p[8][64][16] f32 @32768 ; b2p[8][64][8] f32 @49152 ; a3p[8][64][8] @57344.
__global__ void cvt_pack(const float* __restrict__ W1, const float* __restrict__ b1,
                         const float* __restrict__ W2, const float* __restrict__ b2,
                         const float* __restrict__ W3, short* __restrict__ ws) {
    int i = blockIdx.x * blockDim.x + threadIdx.x;   // 16384 threads
    short* w1p = ws;
    short* w2p = ws + 16384;
    float* b1p = (float*)(ws + 32768);
    float* b2p = b1p + 8192;
    short* a3p = ws + 57344;
    if (i < 16384) {
        {   // w1p: A-frag tile mt. A[m=n][k=8q+j] = W1[d=8q+j][h=hmap(mt,n)]
            int j = i & 7, lane = (i >> 3) & 63, mt = (i >> 9) & 3, e = i >> 11;
            int n = lane & 15, q = lane >> 4;
            int d = 8 * q + j;
            int h = 32 * (mt >> 1) + 8 * (n >> 2) + 4 * (mt & 1) + (n & 3);
            w1p[i] = f2bf_rne(W1[(e * 32 + d) * 64 + h]);
        }
        {   // w2p: A-frag (mt2,kb2). A[m=n][k=8q+j] = W2[h=32kb2+8q+j][h2map(mt2,n)]
            int j = i & 7, lane = (i >> 3) & 63, kb2 = (i >> 9) & 1,
                mt2 = (i >> 10) & 1, e = i >> 11;
            int n = lane & 15, q = lane >> 4;
            int h = 32 * kb2 + 8 * q + j;
            int h2 = 8 * (n >> 2) + 4 * mt2 + (n & 3);
            w2p[i] = f2bf_rne(W2[(e * 64 + h) * 32 + h2]);
        }
    }
    if (i < 8192) {   // b1p[e][lane][mt*4+r] = b1[e][hmap(mt, 4q+r)]
        int idx = i & 15, lane = (i >> 4) & 63, e = i >> 10;
        int mt = idx >> 2, r = idx & 3, q = lane >> 4;
        int h = 32 * (mt >> 1) + 8 * q + 4 * (mt & 1) + r;
        b1p[i] = b1[e * 64 + h];
    }
    if (i < 4096) {
        {   // b2p[e][lane][mt2*4+r] = b2[e][8q+4mt2+r]
            int idx = i & 7, lane = (i >> 3) & 63, e = i >> 9;
            int mt2 = idx >> 2, r = idx & 3, q = lane >> 4;
            b2p[i] = b2[e * 32 + 8 * q + 4 * mt2 + r];
        }
        {   // a3p[e][lane][j] = W3[e][8q+j]  (A-frag, rows replicated)
            int j = i & 7, lane = (i >> 3) & 63, e = i >> 9;
            int q = lane >> 4;
            a3p[i] = f2bf_rne(W3[e * 32 + 8 * q + j]);
        }
    }
}

__attribute__((amdgpu_flat_work_group_size(512, 512), amdgpu_waves_per_eu(3, 4)))
__global__ void moe_main(const float* __restrict__ x,
                         const float* __restrict__ probs,
                         const short* __restrict__ ws,
                         const float* __restrict__ b3,
                         float* __restrict__ out) {
    __shared__ float sbuf[8][RB];
    const int tid = threadIdx.x;
    const int w = tid >> 6, lane = tid & 63, n = lane & 15, q = lane >> 4;

    const short* w1p = ws;
    const short* w2p = ws + 16384;
    const float* b1p = (const float*)(ws + 32768);
    const float* b2p = b1p + 8192;
    const short* a3p = ws + 57344;

    // Loop-invariant per-expert fragments.
    bf16x8 w1f[4];
    #pragma unroll
    for (int mt = 0; mt < 4; ++mt)
        w1f[mt] = *(const bf16x8*)(w1p + ((w * 4 + mt) * 64 + lane) * 8);
    bf16x8 w2f[2][2];
    #pragma unroll
    for (int mt2 = 0; mt2 < 2; ++mt2)
        #pragma unroll
        for (int kb2 = 0; kb2 < 2; ++kb2)
            w2f[mt2][kb2] = *(const bf16x8*)(w2p + (((w * 2 + mt2) * 2 + kb2) * 64 + lane) * 8);
    f32x4 b1f[4];
    #pragma unroll
    for (int mt = 0; mt < 4; ++mt)
        b1f[mt] = *(const f32x4*)(b1p + (w * 64 + lane) * 16 + mt * 4);
    f32x4 b2f[2];
    #pragma unroll
    for (int mt2 = 0; mt2 < 2; ++mt2)
        b2f[mt2] = *(const f32x4*)(b2p + (w * 64 + lane) * 8 + mt2 * 4);
    const bf16x8 a3f = *(const bf16x8*)(a3p + (w * 64 + lane) * 8);
    const float b3v = b3[w];

    const size_t rowbase = (size_t)blockIdx.x * RB;
    // Two independent 16-row tiles per iteration (32 rows), 16 iterations.
    const float* xp0 = x + (rowbase + n) * 32 + q * 8;      // +1024 per iter
    const float* xp1 = xp0 + 16 * 32;
    const float* pp0 = probs + (rowbase + n) * 8 + w;       // +256 per iter
    const float* pp1 = pp0 + 128;
    float* sb = &sbuf[w][n];

    f32x4 xa0 = *(const f32x4*)xp0, xb0 = *(const f32x4*)(xp0 + 4);
    f32x4 xa1 = *(const f32x4*)xp1, xb1 = *(const f32x4*)(xp1 + 4);
    float pb0 = pp0[0], pb1 = pp1[0];

    for (int it = 0; it < RB / 32; ++it) {
        const int adv = (it < RB / 32 - 1) ? 1 : 0;
        xp0 += 1024 * adv; xp1 += 1024 * adv;
        pp0 += 256 * adv;  pp1 += 256 * adv;
        f32x4 na0 = *(const f32x4*)xp0, nb0 = *(const f32x4*)(xp0 + 4);
        f32x4 na1 = *(const f32x4*)xp1, nb1 = *(const f32x4*)(xp1 + 4);
        float npb0 = pp0[0], npb1 = pp1[0];

        // X^T B-fragments: element j = x[row=n][d=8q+j].
        union { bf16x8 v; unsigned u[4]; } xf0, xf1;
        xf0.u[0] = pk2(xa0.x, xa0.y); xf0.u[1] = pk2(xa0.z, xa0.w);
        xf0.u[2] = pk2(xb0.x, xb0.y); xf0.u[3] = pk2(xb0.z, xb0.w);
        xf1.u[0] = pk2(xa1.x, xa1.y); xf1.u[1] = pk2(xa1.z, xa1.w);
        xf1.u[2] = pk2(xb1.x, xb1.y); xf1.u[3] = pk2(xb1.z, xb1.w);

        // Layer 1: 4x mfma 16x16x32 per tile, C-init = b1 fragment.
        // c1[mt].r holds h1 at h = 32*(mt>>1) + 8q + 4*(mt&1) + r.
        f32x4 c1_0[4], c1_1[4];
        #pragma unroll
        for (int mt = 0; mt < 4; ++mt) {
            c1_0[mt] = MFMA32(w1f[mt], xf0.v, b1f[mt]);
            c1_1[mt] = MFMA32(w1f[mt], xf1.v, b1f[mt]);
        }

        // relu + pack into K=32 B-fragments: P[kb2] element j <-> h=32kb2+8q+j.
        union { bf16x8 v; unsigned u[4]; } P0[2], P1[2];
        #pragma unroll
        for (int kb2 = 0; kb2 < 2; ++kb2) {
            const f32x4 lo0 = c1_0[2 * kb2], hi0 = c1_0[2 * kb2 + 1];
            const f32x4 lo1 = c1_1[2 * kb2], hi1 = c1_1[2 * kb2 + 1];
            P0[kb2].u[0] = pk2(fmaxf(lo0.x, 0.f), fmaxf(lo0.y, 0.f));
            P0[kb2].u[1] = pk2(fmaxf(lo0.z, 0.f), fmaxf(lo0.w, 0.f));
            P0[kb2].u[2] = pk2(fmaxf(hi0.x, 0.f), fmaxf(hi0.y, 0.f));
            P0[kb2].u[3] = pk2(fmaxf(hi0.z, 0.f), fmaxf(hi0.w, 0.f));
            P1[kb2].u[0] = pk2(fmaxf(lo1.x, 0.f), fmaxf(lo1.y, 0.f));
            P1[kb2].u[1] = pk2(fmaxf(lo1.z, 0.f), fmaxf(lo1.w, 0.f));
            P1[kb2].u[2] = pk2(fmaxf(hi1.x, 0.f), fmaxf(hi1.y, 0.f));
            P1[kb2].u[3] = pk2(fmaxf(hi1.z, 0.f), fmaxf(hi1.w, 0.f));
        }

        // Layer 2: 2 M-tiles x 2 K-blocks of 16x16x32 per tile, C-init = b2.
        // c2[mt2].r holds h2-pre-act at h2 = 8q + 4*mt2 + r.
        f32x4 c2_0[2], c2_1[2];
        #pragma unroll
        for (int mt2 = 0; mt2 < 2; ++mt2) {
            f32x4 a0 = b2f[mt2], a1 = b2f[mt2];
            a0 = MFMA32(w2f[mt2][0], P0[0].v, a0);
            a1 = MFMA32(w2f[mt2][0], P1[0].v, a1);
            a0 = MFMA32(w2f[mt2][1], P0[1].v, a0);
            a1 = MFMA32(w2f[mt2][1], P1[1].v, a1);
            c2_0[mt2] = a0; c2_1[mt2] = a1;
        }

        // relu + pack H2 -> K=32 B-fragment: element j <-> h2 = 8q+j.
        union { bf16x8 v; unsigned u[4]; } PC0, PC1;
        PC0.u[0] = pk2(fmaxf(c2_0[0].x, 0.f), fmaxf(c2_0[0].y, 0.f));
        PC0.u[1] = pk2(fmaxf(c2_0[0].z, 0.f), fmaxf(c2_0[0].w, 0.f));
        PC0.u[2] = pk2(fmaxf(c2_0[1].x, 0.f), fmaxf(c2_0[1].y, 0.f));
        PC0.u[3] = pk2(fmaxf(c2_0[1].z, 0.f), fmaxf(c2_0[1].w, 0.f));
        PC1.u[0] = pk2(fmaxf(c2_1[0].x, 0.f), fmaxf(c2_1[0].y, 0.f));
        PC1.u[1] = pk2(fmaxf(c2_1[0].z, 0.f), fmaxf(c2_1[0].w, 0.f));
        PC1.u[2] = pk2(fmaxf(c2_1[1].x, 0.f), fmaxf(c2_1[1].y, 0.f));
        PC1.u[3] = pk2(fmaxf(c2_1[1].z, 0.f), fmaxf(c2_1[1].w, 0.f));

        // Layer 3: one 16x16x32 MFMA, A = w3 replicated -> D[m][n]=s[n].
        f32x4 b3c = {b3v, b3v, b3v, b3v};
        f32x4 s0 = MFMA32(a3f, PC0.v, b3c);
        f32x4 s1 = MFMA32(a3f, PC1.v, b3c);

        const float sig0 = 1.f / (1.f + __expf(-s0.x));
        const float sig1 = 1.f / (1.f + __expf(-s1.x));
        if (q == 0) {
            sb[it * 32]      = sig0 * pb0;
            sb[it * 32 + 16] = sig1 * pb1;
        }

        xa0 = na0; xb0 = nb0; xa1 = na1; xb1 = nb1;
        pb0 = npb0; pb1 = npb1;
    }

    __syncthreads();
    // Combine experts: thread t sums sbuf[0..7][t]; coalesced 2 KB store.
    float r = 0.f;
    #pragma unroll
    for (int e = 0; e < 8; ++e) r += sbuf[e][tid];
    out[rowbase + tid] = r;
}

extern "C" void kernel_launch(void* const* d_in, const int* in_sizes, int n_in,
                              void* d_out, int out_size, void* d_ws, size_t ws_size,
                              hipStream_t stream) {
    const float* x     = (const float*)d_in[0];
    const float* probs = (const float*)d_in[1];
    const float* W1    = (const float*)d_in[2];
    const float* b1    = (const float*)d_in[3];
    const float* W2    = (const float*)d_in[4];
    const float* b2    = (const float*)d_in[5];
    const float* W3    = (const float*)d_in[6];
    const float* b3    = (const float*)d_in[7];

    short* ws = (short*)d_ws;
    const int nrows = in_sizes[0] / 32;          // 524288

    hipLaunchKernelGGL(cvt_pack, dim3(64), dim3(256), 0, stream,
                       W1, b1, W2, b2, W3, ws);
    hipLaunchKernelGGL(moe_main, dim3(nrows / RB), dim3(512), 0, stream,
                       x, probs, ws, b3, (float*)d_out);
}

// Round 11
// 175.663 us; speedup vs baseline: 1.0975x; 1.0823x over previous
//
#include <hip/hip_runtime.h>

// EnhancedMoEModel: B=524288, D=32, H=64, H2=32, E=8, O=1. fp32 in/out.
// out[b] = sum_e sigmoid(relu(relu(x W1e + b1e) W2e + b2e) W3e + b3e) * probs[b,e]
//
// R11: occupancy rewrite. R5-R10 all pinned at ~105us / 41% occupancy: the
// 61-reg expert-stationary weight set forces ~124 unified regs -> 4 waves/EU
// (pool 512, halving quantization). This version puts W1/W2 bf16 fragments
// in 64 KB LDS shared by a 1024-thread block (16 waves own 32 rows each,
// expert loop inner -> loop-variant LDS addresses, nothing to hoist),
// biases/W3/probs straight from global (broadcast, L1-hot). Single launch.
// Target: <=64 VGPRs, 2 blocks/CU, 100% occupancy.
//
// Fragment math (verified R8/R10 end-to-end): 16x16x32 bf16 MFMA with
//   A[m=lane&15][k=8q+j], B[k=8q+j][n=lane&15], D[m=4q+r][n]: per-lane reg r.
// Hidden-unit column permutation hmap(mt,n)=32(mt>>1)+8(n>>2)+4(mt&1)+(n&3)
// makes layer-N output registers exactly the next layer's B-fragment.

typedef __attribute__((ext_vector_type(8))) short bf16x8;
typedef __attribute__((ext_vector_type(4))) float f32x4;

__device__ __forceinline__ unsigned pk2(float lo, float hi) {
#if __has_builtin(__builtin_amdgcn_cvt_pk_bf16_f32)
    typedef __attribute__((ext_vector_type(2))) __bf16 nbf2;
    union { nbf2 v; unsigned u; } t;
    t.v = __builtin_amdgcn_cvt_pk_bf16_f32(lo, hi);
    return t.u;
#else
    unsigned ulo = __float_as_uint(lo) + 0x8000u;
    unsigned uhi = __float_as_uint(hi) + 0x8000u;
    return __builtin_amdgcn_perm(uhi, ulo, 0x07060302u);
#endif
}

#define MFMA32(a, b, c) __builtin_amdgcn_mfma_f32_16x16x32_bf16((a), (b), (c), 0, 0, 0)

__global__ __launch_bounds__(1024, 8)
void moe_fused(const float* __restrict__ x, const float* __restrict__ probs,
               const float* __restrict__ W1, const float* __restrict__ b1,
               const float* __restrict__ W2, const float* __restrict__ b2,
               const float* __restrict__ W3, const float* __restrict__ b3,
               float* __restrict__ out) {
    // LDS image, 16-B fragments, byte addr = F*16:
    //   w1: F = e*256 + 64*mt + 16*q + n      (F in [0,2048))
    //   w2: F = 2048 + e*256 + 128*kb2 + 64*mt2 + 16*q + n
    // Reader banks: words = (n*4 + ...) mod 32 -> n mod 8 spread, 2-way max.
    __shared__ short wlds[32768];   // 64 KB exactly
    const int tid = threadIdx.x;
    const int w = tid >> 6, lane = tid & 63, n = lane & 15, q = lane >> 4;

    // ---- prologue: each thread builds 4 fragments (64 B) of the LDS image.
    #pragma unroll
    for (int k = 0; k < 4; ++k) {
        const int F = tid * 4 + k;
        const int e = (F >> 8) & 7, s = F & 255;
        const int qq = (s >> 4) & 3, nn = s & 15;
        const float* src;
        int stride;
        if (F < 2048) {          // W1[e][d=8qq+j][hmap(mt,nn)], j strides d
            const int mt = s >> 6;
            const int h = 32 * (mt >> 1) + 8 * (nn >> 2) + 4 * (mt & 1) + (nn & 3);
            src = W1 + (e * 32 + 8 * qq) * 64 + h;
            stride = 64;
        } else {                 // W2[e][h=32kb2+8qq+j][h2map(mt2,nn)], j strides h
            const int kb2 = (s >> 7) & 1, mt2 = (s >> 6) & 1;
            const int h2 = 8 * (nn >> 2) + 4 * mt2 + (nn & 3);
            src = W2 + (e * 64 + 32 * kb2 + 8 * qq) * 32 + h2;
            stride = 32;
        }
        union { bf16x8 v; unsigned u[4]; } t;
        t.u[0] = pk2(src[0 * stride], src[1 * stride]);
        t.u[1] = pk2(src[2 * stride], src[3 * stride]);
        t.u[2] = pk2(src[4 * stride], src[5 * stride]);
        t.u[3] = pk2(src[6 * stride], src[7 * stride]);
        *(bf16x8*)(wlds + F * 8) = t.v;
    }

    // ---- per-wave x tiles: wave owns rows rb..rb+31 (two 16-row tiles).
    const int rb = blockIdx.x * 512 + w * 32;
    const float* xp0 = x + (size_t)(rb + n) * 32 + q * 8;
    const float* xp1 = xp0 + 16 * 32;
    const f32x4 xa0 = *(const f32x4*)xp0, xb0 = *(const f32x4*)(xp0 + 4);
    const f32x4 xa1 = *(const f32x4*)xp1, xb1 = *(const f32x4*)(xp1 + 4);
    union { bf16x8 v; unsigned u[4]; } xf0, xf1;
    xf0.u[0] = pk2(xa0.x, xa0.y); xf0.u[1] = pk2(xa0.z, xa0.w);
    xf0.u[2] = pk2(xb0.x, xb0.y); xf0.u[3] = pk2(xb0.z, xb0.w);
    xf1.u[0] = pk2(xa1.x, xa1.y); xf1.u[1] = pk2(xa1.z, xa1.w);
    xf1.u[2] = pk2(xb1.x, xb1.y); xf1.u[3] = pk2(xb1.z, xb1.w);

    __syncthreads();

    const short* wl = wlds + (n * 8 + q * 128);   // + e*2048/iter; imms do the rest
    const float* b1a = b1 + 8 * q;
    const float* b2a = b2 + 8 * q;
    const float* w3a = W3 + 8 * q;
    const float* pba = probs + (size_t)(rb + n) * 8;
    float r0 = 0.f, r1 = 0.f;

    #pragma unroll 1
    for (int e = 0; e < 8; ++e) {
        const float pb0 = pba[e], pb1 = pba[e + 128];
        const short* we = wl + e * 2048;

        // Layer 1: 4 mt-tiles; w1f shared by both row-tiles. relu+pack into
        // K=32 B-fragments P[kb2] (element j <-> h = 32kb2 + 8q + j).
        union { bf16x8 v; unsigned u[4]; } P0[2], P1[2];
        #pragma unroll
        for (int mt = 0; mt < 4; ++mt) {
            const bf16x8 w1f = *(const bf16x8*)(we + mt * 512);
            const f32x4 bf = *(const f32x4*)(b1a + e * 64 + 32 * (mt >> 1) + 4 * (mt & 1));
            const f32x4 c0 = MFMA32(w1f, xf0.v, bf);
            const f32x4 c1 = MFMA32(w1f, xf1.v, bf);
            P0[mt >> 1].u[(mt & 1) * 2 + 0] = pk2(fmaxf(c0.x, 0.f), fmaxf(c0.y, 0.f));
            P0[mt >> 1].u[(mt & 1) * 2 + 1] = pk2(fmaxf(c0.z, 0.f), fmaxf(c0.w, 0.f));
            P1[mt >> 1].u[(mt & 1) * 2 + 0] = pk2(fmaxf(c1.x, 0.f), fmaxf(c1.y, 0.f));
            P1[mt >> 1].u[(mt & 1) * 2 + 1] = pk2(fmaxf(c1.z, 0.f), fmaxf(c1.w, 0.f));
        }

        // Layer 2: 2 mt2 x 2 kb2; relu+pack into PC (element j <-> h2 = 8q+j).
        union { bf16x8 v; unsigned u[4]; } PC0, PC1;
        #pragma unroll
        for (int mt2 = 0; mt2 < 2; ++mt2) {
            const f32x4 bf = *(const f32x4*)(b2a + e * 32 + 4 * mt2);
            f32x4 c0 = bf, c1 = bf;
            #pragma unroll
            for (int kb2 = 0; kb2 < 2; ++kb2) {
                const bf16x8 w2f =
                    *(const bf16x8*)(we + 16384 + mt2 * 512 + kb2 * 1024);
                c0 = MFMA32(w2f, P0[kb2].v, c0);
                c1 = MFMA32(w2f, P1[kb2].v, c1);
            }
            PC0.u[mt2 * 2 + 0] = pk2(fmaxf(c0.x, 0.f), fmaxf(c0.y, 0.f));
            PC0.u[mt2 * 2 + 1] = pk2(fmaxf(c0.z, 0.f), fmaxf(c0.w, 0.f));
            PC1.u[mt2 * 2 + 0] = pk2(fmaxf(c1.x, 0.f), fmaxf(c1.y, 0.f));
            PC1.u[mt2 * 2 + 1] = pk2(fmaxf(c1.z, 0.f), fmaxf(c1.w, 0.f));
        }

        // Layer 3: A = w3 replicated over rows -> D[m][n] = s[n] for all m.
        const f32x4 w3lo = *(const f32x4*)(w3a + e * 32);
        const f32x4 w3hi = *(const f32x4*)(w3a + e * 32 + 4);
        union { bf16x8 v; unsigned u[4]; } a3;
        a3.u[0] = pk2(w3lo.x, w3lo.y); a3.u[1] = pk2(w3lo.z, w3lo.w);
        a3.u[2] = pk2(w3hi.x, w3hi.y); a3.u[3] = pk2(w3hi.z, w3hi.w);
        const f32x4 z = {0.f, 0.f, 0.f, 0.f};
        const f32x4 s0 = MFMA32(a3.v, PC0.v, z);
        const f32x4 s1 = MFMA32(a3.v, PC1.v, z);

        const float bb = b3[e];   // wave-uniform -> scalar load
        r0 = fmaf(1.f / (1.f + __expf(-(s0.x + bb))), pb0, r0);
        r1 = fmaf(1.f / (1.f + __expf(-(s1.x + bb))), pb1, r1);
    }

    if (q == 0) {
        out[rb + n] = r0;
        out[rb + 16 + n] = r1;
    }
}

extern "C" void kernel_launch(void* const* d_in, const int* in_sizes, int n_in,
                              void* d_out, int out_size, void* d_ws, size_t ws_size,
                              hipStream_t stream) {
    const float* x     = (const float*)d_in[0];
    const float* probs = (const float*)d_in[1];
    const float* W1    = (const float*)d_in[2];
    const float* b1    = (const float*)d_in[3];
    const float* W2    = (const float*)d_in[4];
    const float* b2    = (const float*)d_in[5];
    const float* W3    = (const float*)d_in[6];
    const float* b3    = (const float*)d_in[7];

    const int nrows = in_sizes[0] / 32;          // 524288
    hipLaunchKernelGGL(moe_fused, dim3(nrows / 512), dim3(1024), 0, stream,
                       x, probs, W1, b1, W2, b2, W3, b3, (float*)d_out);
}